// Round 16
// baseline (305.907 us; speedup 1.0000x reference)
//
#include <hip/hip_runtime.h>
#include <hip/hip_bf16.h>

// sqllm 4-bit GEMM: out[m,n] = sum_k A[m,k] * lut[n, nibble(qweight[k/8,n], k%8)]
// M=8192, N=4096, K=4096. PRE path: A->bf16, W dequant once into ws.
// GEMM: 256x256, 8 waves, 4-slot LDS ring, all global_load_lds staging.
// Schedule = R14's proven one (asm ds_read "=v" cluster after vmcnt, before
// MFMA block, lgkm0 after — R15's interleave REVERTED: MFMA-src WAR with
// opaque asm defs corrupted results). New: 32x32x16 MFMA (matrix term -17%,
// MFMA instruction count halved).

typedef __attribute__((ext_vector_type(4)))  float f32x4;
typedef __attribute__((ext_vector_type(16))) float f32x16;
typedef __attribute__((ext_vector_type(4)))  int   i32x4;
typedef __attribute__((ext_vector_type(8)))  short bf16x8;

__device__ __forceinline__ unsigned short f2bf(float f) {
    __hip_bfloat16 h = __float2bfloat16(f);
    return __builtin_bit_cast(unsigned short, h);
}

__device__ __forceinline__ void gload16(const unsigned short* g, unsigned short* l) {
    __builtin_amdgcn_global_load_lds(
        (const __attribute__((address_space(1))) unsigned int*)g,
        (__attribute__((address_space(3))) unsigned int*)l, 16, 0, 0);
}

// ---------------- prepass kernels ----------------

__global__ void convA_kernel(const float* __restrict__ in, unsigned short* __restrict__ o, long n8) {
    long i = (long)blockIdx.x * blockDim.x + threadIdx.x;
    long stride = (long)gridDim.x * blockDim.x;
    const f32x4* in4 = reinterpret_cast<const f32x4*>(in);
    bf16x8* o8 = reinterpret_cast<bf16x8*>(o);
    for (; i < n8; i += stride) {
        f32x4 a = in4[2 * i];
        f32x4 b = in4[2 * i + 1];
        bf16x8 e;
#pragma unroll
        for (int x = 0; x < 4; ++x) {
            e[x]     = (short)f2bf(a[x]);
            e[4 + x] = (short)f2bf(b[x]);
        }
        o8[i] = e;
    }
}

__global__ void dequantW_kernel(const int* __restrict__ Q, const float* __restrict__ lut,
                                unsigned short* __restrict__ Wb, int N, long total) {
    long i = (long)blockIdx.x * blockDim.x + threadIdx.x;
    if (i >= total) return;
    unsigned int v = (unsigned int)Q[i];
    int n = (int)(i % N);
    const float* lp = lut + (long)n * 16;
    bf16x8 w;
#pragma unroll
    for (int p = 0; p < 8; ++p)
        w[p] = (short)f2bf(lp[(v >> (4 * p)) & 15]);
    reinterpret_cast<bf16x8*>(Wb)[i] = w;
}

// ---------------- 256x256 GEMM, 32x32x16 MFMA, R14 schedule ----------------
// Half H -> slot H&3. Phase H:
//   stage(H+3)  [4 gload_lds];  vmcnt(8) (forces stage(H+1) landed)
//   12x asm ds_read_b128 (slot (H+1)&3) -> alt regs   (defs before CA's last
//   use -> distinct registers; no interleave with MFMAs — R15 lesson)
//   sched_barrier; setprio(1); 16x mfma_32x32x16 on current regs; setprio(0)
//   lgkmcnt(0); sched_barrier; s_barrier
// Frag layout (32x32x16): A row=lane&31, k-oct=(lane>>5)+2*ks;
//                         B col=lane&31, same k-oct. NA[ks*4+ma], NB[ks*2+nb].

#define DSR(dst, addr, OFF) \
    asm volatile("ds_read_b128 %0, %1 offset:" #OFF : "=v"(dst) : "v"(addr))

#define LOADFRAGS_ASM(NA, NB, SLOT) do {                                          \
    unsigned a0_ = aByte0 + (unsigned)(SLOT) * 16384u;                            \
    unsigned a1_ = aByte1 + (unsigned)(SLOT) * 16384u;                            \
    unsigned bb_ = bByte  + (unsigned)(SLOT) * 16384u;                            \
    DSR(NB[0], bb_, 0);    DSR(NB[1], bb_, 512);                                  \
    DSR(NB[2], bb_, 8192); DSR(NB[3], bb_, 8704);                                 \
    DSR(NA[0], a0_, 0);    DSR(NA[1], a0_, 2048);                                 \
    DSR(NA[2], a0_, 4096); DSR(NA[3], a0_, 6144);                                 \
    DSR(NA[4], a1_, 0);    DSR(NA[5], a1_, 2048);                                 \
    DSR(NA[6], a1_, 4096); DSR(NA[7], a1_, 6144);                                 \
} while (0)

#define MFMABLOCK(CA, CB)                                                         \
    _Pragma("unroll") for (int ks = 0; ks < 2; ++ks)                              \
        _Pragma("unroll") for (int ma = 0; ma < 4; ++ma)                          \
            _Pragma("unroll") for (int nb = 0; nb < 2; ++nb)                      \
                acc[ma][nb] = __builtin_amdgcn_mfma_f32_32x32x16_bf16(            \
                    CA[ks * 4 + ma], CB[ks * 2 + nb], acc[ma][nb], 0, 0, 0);

#define PHASE(U, CA, CB, NA, NB) do {                                             \
    int S3 = H + (U) + 3; if (S3 >= NH) S3 -= NH;                                 \
    stage(S3, ((U) + 3) & 3);                                                     \
    asm volatile("s_waitcnt vmcnt(8)" ::: "memory");                              \
    LOADFRAGS_ASM(NA, NB, ((U) + 1) & 3);                                         \
    __builtin_amdgcn_sched_barrier(0);                                            \
    __builtin_amdgcn_s_setprio(1);                                                \
    MFMABLOCK(CA, CB)                                                             \
    __builtin_amdgcn_s_setprio(0);                                                \
    asm volatile("s_waitcnt lgkmcnt(0)" ::: "memory");                            \
    __builtin_amdgcn_sched_barrier(0);                                            \
    __builtin_amdgcn_s_barrier();                                                 \
} while (0)

__global__ __launch_bounds__(512, 2)
void gemm8p(const unsigned short* __restrict__ Abf, const unsigned short* __restrict__ Wb,
            float* __restrict__ out, int M, int N, int K) {
    __shared__ __align__(16) unsigned short sA[4 * 8192];  // 4 slots x 256m x 32k (kc swz)
    __shared__ __align__(16) unsigned short sB[4 * 8192];  // 4 slots x 4kc x 256n x 8

    const int tid  = threadIdx.x;
    const int lane = tid & 63;
    const int wid  = tid >> 6;
    const int wr   = wid >> 2;   // 0..1  (128-row half)
    const int wc   = wid & 3;    // 0..3  (64-col slice)
    const int l31  = lane & 31;
    const int hi2  = lane >> 5;  // 0..1

    const int NBN = N / 256;
    int nwg = gridDim.x, orig = blockIdx.x;
    int wg = ((nwg & 7) == 0) ? (orig & 7) * (nwg >> 3) + (orig >> 3) : orig;
    const int m0 = (wg / NBN) * 256, n0 = (wg % NBN) * 256;

    const int NH = K / 32;  // 32-k halves (NH % 4 == 0)

    // per-lane frag element offsets (ushorts) for 32x32x16 operand layout
    const int m_l = wr * 128 + l31;
    const int s_  = (m_l >> 1) & 3;
    const int eA0 = m_l * 32 + (((hi2)     ^ s_) << 3);  // ks=0: kc = hi2
    const int eA1 = m_l * 32 + (((hi2 + 2) ^ s_) << 3);  // ks=1: kc = hi2+2
    const int n_l = wc * 64 + l31;
    const int eB0 = hi2 * 2048 + n_l * 8;                // ks via +8192B imm
    const unsigned aByte0 = (unsigned)(unsigned long long)
        ((__attribute__((address_space(3))) unsigned short*)sA + eA0);
    const unsigned aByte1 = (unsigned)(unsigned long long)
        ((__attribute__((address_space(3))) unsigned short*)sA + eA1);
    const unsigned bByte  = (unsigned)(unsigned long long)
        ((__attribute__((address_space(3))) unsigned short*)sB + eB0);

    // staging bases: 2 A + 2 B gload_lds per thread per half (as R14)
    const int am  = tid >> 2, akc = tid & 3;
    const int akcs = (akc ^ ((am >> 1) & 3)) << 3;
    const unsigned short* baseA0 = Abf + (size_t)(m0 + am) * K + akcs;
    const unsigned short* baseA1 = Abf + (size_t)(m0 + am + 128) * K + akcs;
    const int bkc = tid >> 8, bn = tid & 255;
    const unsigned short* baseB0 = Wb + ((size_t)bkc * N + n0 + bn) * 8;
    const unsigned short* baseB1 = Wb + ((size_t)(bkc + 2) * N + n0 + bn) * 8;
    const size_t bstride = (size_t)32 * N;
    unsigned short* const dA = sA + wid * 512;
    unsigned short* const dB = sB + wid * 512;

    auto stage = [&](int S, int slot) {
        gload16(baseA0 + S * 32, dA + slot * 8192);
        gload16(baseB0 + S * bstride, dB + slot * 8192);
        gload16(baseA1 + S * 32, dA + slot * 8192 + 4096);
        gload16(baseB1 + S * bstride, dB + slot * 8192 + 4096);
    };

    f32x16 acc[4][2] = {};
    bf16x8 avA[8], bvA[4], avB[8], bvB[4];

    // prologue: stage halves 0,1,2; vmcnt(8) forces slot 0; barrier;
    // plain-load frags(0) (compiler inserts lgkm wait before first MFMA)
    stage(0, 0);
    stage(1, 1);
    stage(2, 2);
    asm volatile("s_waitcnt vmcnt(8)" ::: "memory");
    __builtin_amdgcn_s_barrier();
#pragma unroll
    for (int ks = 0; ks < 2; ++ks)
#pragma unroll
        for (int nb = 0; nb < 2; ++nb)
            bvA[ks * 2 + nb] = *(const bf16x8*)(sB + eB0 + ks * 4096 + nb * 256);
#pragma unroll
    for (int ma = 0; ma < 4; ++ma) {
        avA[ma]     = *(const bf16x8*)(sA + eA0 + ma * 1024);
        avA[4 + ma] = *(const bf16x8*)(sA + eA1 + ma * 1024);
    }

    for (int H = 0; H < NH; H += 4) {
        PHASE(0, avA, bvA, avB, bvB);
        PHASE(1, avB, bvB, avA, bvA);
        PHASE(2, avA, bvA, avB, bvB);
        PHASE(3, avB, bvB, avA, bvA);
    }

    asm volatile("s_waitcnt vmcnt(0)" ::: "memory");  // drain wrap prefetches

    // epilogue: 32x32 C/D layout col=lane&31, row=(reg&3)+8*(reg>>2)+4*(lane>>5)
#pragma unroll
    for (int ma = 0; ma < 4; ++ma) {
#pragma unroll
        for (int nb = 0; nb < 2; ++nb) {
            const int ncol = n0 + wc * 64 + nb * 32 + l31;
            const int rbase = m0 + wr * 128 + ma * 32 + 4 * hi2;
#pragma unroll
            for (int g = 0; g < 4; ++g) {
                float* po = out + (size_t)(rbase + g * 8) * N + ncol;
#pragma unroll
                for (int rr = 0; rr < 4; ++rr)
                    po[(size_t)rr * N] = acc[ma][nb][g * 4 + rr];
            }
        }
    }
}

#undef PHASE
#undef MFMABLOCK
#undef LOADFRAGS_ASM
#undef DSR

// ---------------- fallback fused kernel (small ws only) ----------------

#define FBM 128
#define FBN 128
#define FBK 64

__device__ __forceinline__ int fswz(int row, int kb) {
    return row * (FBK * 2) + (kb ^ ((row & 7) << 4));
}

__global__ __launch_bounds__(256, 2)
void sqllm_gemm_fused(const float* __restrict__ A, const int* __restrict__ Q,
                      const float* __restrict__ lut, float* __restrict__ out,
                      int M, int N, int K) {
    __shared__ __align__(16) char sA[FBM * FBK * 2];
    __shared__ __align__(16) char sB[FBN * FBK * 2];
    __shared__ float sLut[FBN * 17];

    const int tid  = threadIdx.x;
    const int lane = tid & 63;
    const int wid  = tid >> 6;
    const int wr   = wid >> 1;
    const int wc   = wid & 1;
    const int n0 = blockIdx.x * FBN;
    const int m0 = blockIdx.y * FBM;

    for (int i = tid; i < FBN * 16; i += 256) {
        int n = i >> 4, c = i & 15;
        sLut[n * 17 + c] = lut[(long)(n0 + n) * 16 + c];
    }
    __syncthreads();

    f32x4 acc[4][4] = {};
    const int nK = K / FBK;
    for (int kk = 0; kk < nK; ++kk) {
        {
            const int r = tid >> 1, h = tid & 1;
            const float* ap = A + (long)(m0 + r) * K + kk * FBK + h * 32;
            f32x4 v[8];
#pragma unroll
            for (int j = 0; j < 8; ++j) v[j] = reinterpret_cast<const f32x4*>(ap)[j];
            const int kr = tid >> 5, nq = (tid & 31) << 2;
            const int* qp = Q + (long)(kk * (FBK / 8) + kr) * N + n0 + nq;
            i32x4 q = *reinterpret_cast<const i32x4*>(qp);
#pragma unroll
            for (int j = 0; j < 4; ++j) {
                bf16x8 e;
#pragma unroll
                for (int x = 0; x < 4; ++x) {
                    e[x]     = (short)f2bf(v[2 * j][x]);
                    e[4 + x] = (short)f2bf(v[2 * j + 1][x]);
                }
                *reinterpret_cast<bf16x8*>(sA + fswz(r, h * 64 + j * 16)) = e;
            }
#pragma unroll
            for (int c = 0; c < 4; ++c) {
                const int n = nq + c;
                const float* lp = sLut + n * 17;
                unsigned int qq = (unsigned int)q[c];
                bf16x8 w;
#pragma unroll
                for (int p = 0; p < 8; ++p)
                    w[p] = (short)f2bf(lp[(qq >> (4 * p)) & 15]);
                *reinterpret_cast<bf16x8*>(sB + fswz(n, kr * 16)) = w;
            }
        }
        __syncthreads();
#pragma unroll
        for (int kh = 0; kh < 2; ++kh) {
            const int kb = kh * 64 + (lane >> 4) * 16;
            bf16x8 af[4], bfv[4];
#pragma unroll
            for (int i = 0; i < 4; ++i) {
                af[i]  = *reinterpret_cast<const bf16x8*>(sA + fswz(wr * 64 + i * 16 + (lane & 15), kb));
                bfv[i] = *reinterpret_cast<const bf16x8*>(sB + fswz(wc * 64 + i * 16 + (lane & 15), kb));
            }
#pragma unroll
            for (int i = 0; i < 4; ++i)
#pragma unroll
                for (int j = 0; j < 4; ++j)
                    acc[i][j] = __builtin_amdgcn_mfma_f32_16x16x32_bf16(af[i], bfv[j], acc[i][j], 0, 0, 0);
        }
        __syncthreads();
    }
    const int col = lane & 15;
    const int r4  = (lane >> 4) * 4;
#pragma unroll
    for (int i = 0; i < 4; ++i) {
        const int mrow = m0 + wr * 64 + i * 16 + r4;
#pragma unroll
        for (int j = 0; j < 4; ++j) {
            const int ncol = n0 + wc * 64 + j * 16 + col;
#pragma unroll
            for (int r = 0; r < 4; ++r)
                out[(long)(mrow + r) * N + ncol] = acc[i][j][r];
        }
    }
}

extern "C" void kernel_launch(void* const* d_in, const int* in_sizes, int n_in,
                              void* d_out, int out_size, void* d_ws, size_t ws_size,
                              hipStream_t stream) {
    const float* A   = (const float*)d_in[0];
    const int*   Q   = (const int*)d_in[1];
    const float* lut = (const float*)d_in[2];
    float* out = (float*)d_out;

    const long szA = in_sizes[0], szQ = in_sizes[1], szL = in_sizes[2];
    const int N = (int)(szL / 16);
    const int K = (int)(szQ * 8 / N);
    const int M = (int)(szA / K);

    const size_t needA = (size_t)M * K * 2;
    const size_t needW = (size_t)K * N * 2;

    const bool shape_ok = (M % 256 == 0) && (N % 256 == 0) && (K % 128 == 0);

    if (shape_ok && ws_size >= needA + needW) {
        unsigned short* Abf = (unsigned short*)d_ws;
        unsigned short* Wb  = (unsigned short*)((char*)d_ws + needA);
        const long n8 = (long)M * K / 8;
        convA_kernel<<<2048, 256, 0, stream>>>(A, Abf, n8);
        const long tq = (long)(K / 8) * N;
        dequantW_kernel<<<(int)((tq + 255) / 256), 256, 0, stream>>>(Q, lut, Wb, N, tq);
        dim3 grid((M / 256) * (N / 256));
        gemm8p<<<grid, 512, 0, stream>>>(Abf, Wb, out, M, N, K);
    } else {
        dim3 grid(N / FBN, M / FBM);
        sqllm_gemm_fused<<<grid, 256, 0, stream>>>(A, Q, lut, out, M, N, K);
    }
}

// Round 18
// 279.763 us; speedup vs baseline: 1.0935x; 1.0935x over previous
//
#include <hip/hip_runtime.h>
#include <hip/hip_bf16.h>

// sqllm 4-bit GEMM: out[m,n] = sum_k A[m,k] * lut[n, nibble(qweight[k/8,n], k%8)]
// M=8192, N=4096, K=4096. PRE path: A->bf16, W dequant once into ws.
// GEMM: 256x256, 8 waves, 4-slot LDS ring, all global_load_lds staging,
// 16x16x32 MFMA. EXACT R14 schedule (best passing, 234.6us) with ONE
// strictly-stronger fix: vmcnt(8)->vmcnt(4) everywhere (incl. prologue),
// making the cross-wave staging ledger proven instead of latency-lucky.
// R17's counted lgkmcnt(12) REVERTED: lgkm counts mixed op classes
// (possibly incl. global_load_lds) -> count unprovable -> stale frags.
// Safe rules learned: counted vmcnt only over pure-gload_lds; lgkm only
// as full drain lgkmcnt(0); asm ds_read defs clustered (no MFMA interleave).

typedef __attribute__((ext_vector_type(4))) float  f32x4;
typedef __attribute__((ext_vector_type(4))) int    i32x4;
typedef __attribute__((ext_vector_type(8))) short  bf16x8;

__device__ __forceinline__ unsigned short f2bf(float f) {
    __hip_bfloat16 h = __float2bfloat16(f);
    return __builtin_bit_cast(unsigned short, h);
}

__device__ __forceinline__ void gload16(const unsigned short* g, unsigned short* l) {
    __builtin_amdgcn_global_load_lds(
        (const __attribute__((address_space(1))) unsigned int*)g,
        (__attribute__((address_space(3))) unsigned int*)l, 16, 0, 0);
}

// ---------------- prepass kernels ----------------

__global__ void convA_kernel(const float* __restrict__ in, unsigned short* __restrict__ o, long n8) {
    long i = (long)blockIdx.x * blockDim.x + threadIdx.x;
    long stride = (long)gridDim.x * blockDim.x;
    const f32x4* in4 = reinterpret_cast<const f32x4*>(in);
    bf16x8* o8 = reinterpret_cast<bf16x8*>(o);
    for (; i < n8; i += stride) {
        f32x4 a = in4[2 * i];
        f32x4 b = in4[2 * i + 1];
        bf16x8 e;
#pragma unroll
        for (int x = 0; x < 4; ++x) {
            e[x]     = (short)f2bf(a[x]);
            e[4 + x] = (short)f2bf(b[x]);
        }
        o8[i] = e;
    }
}

__global__ void dequantW_kernel(const int* __restrict__ Q, const float* __restrict__ lut,
                                unsigned short* __restrict__ Wb, int N, long total) {
    long i = (long)blockIdx.x * blockDim.x + threadIdx.x;
    if (i >= total) return;
    unsigned int v = (unsigned int)Q[i];
    int n = (int)(i % N);
    const float* lp = lut + (long)n * 16;
    bf16x8 w;
#pragma unroll
    for (int p = 0; p < 8; ++p)
        w[p] = (short)f2bf(lp[(v >> (4 * p)) & 15]);
    reinterpret_cast<bf16x8*>(Wb)[i] = w;
}

// ---------------- 256x256 GEMM, R14 schedule + proven vmcnt(4) ledger -------
// Half H -> slot H&3. Phase H:
//   stage(H+3)  [4 gload_lds]
//   vmcnt(4)    (outstanding {stage(H+2),stage(H+3)}=8 -> forces stage(H+2);
//                stage(H+1) was forced at phase H-1's vmcnt(4), BEFORE that
//                phase's barrier -> cross-wave proof for this phase's reads)
//   12x asm ds_read_b128 (slot (H+1)&3) -> alt regs ("=v": distinct regs,
//                breaks the allocator WAR interlock - R14's +11.5% win)
//   sched_barrier; setprio(1); 32 MFMA on current regs; setprio(0)
//   lgkmcnt(0); sched_barrier; s_barrier   (full DS drain - provably safe)
// LDS WAR: slot (H+1)'s reads drain at phase H's lgkmcnt(0), >=1 barrier
// before its re-staging in phase H+2.

#define DSR(dst, addr, OFF) \
    asm volatile("ds_read_b128 %0, %1 offset:" #OFF : "=v"(dst) : "v"(addr))

#define LOADFRAGS_ASM(NA, NB, SLOT) do {                                          \
    unsigned ab_ = aByte + (unsigned)(SLOT) * 16384u;                             \
    unsigned bb_ = bByte + (unsigned)(SLOT) * 16384u;                             \
    DSR(NB[0], bb_, 0);    DSR(NB[1], bb_, 256);                                  \
    DSR(NB[2], bb_, 512);  DSR(NB[3], bb_, 768);                                  \
    DSR(NA[0], ab_, 0);    DSR(NA[1], ab_, 1024);                                 \
    DSR(NA[2], ab_, 2048); DSR(NA[3], ab_, 3072);                                 \
    DSR(NA[4], ab_, 4096); DSR(NA[5], ab_, 5120);                                 \
    DSR(NA[6], ab_, 6144); DSR(NA[7], ab_, 7168);                                 \
} while (0)

#define MFMABLOCK(CA, CB)                                                         \
    _Pragma("unroll") for (int mf = 0; mf < 8; ++mf)                              \
        _Pragma("unroll") for (int nf = 0; nf < 4; ++nf)                          \
            acc[mf][nf] = __builtin_amdgcn_mfma_f32_16x16x32_bf16(                \
                CA[mf], CB[nf], acc[mf][nf], 0, 0, 0);

#define PHASE(U, CA, CB, NA, NB) do {                                             \
    int S3 = H + (U) + 3; if (S3 >= NH) S3 -= NH;                                 \
    stage(S3, ((U) + 3) & 3);                                                     \
    asm volatile("s_waitcnt vmcnt(4)" ::: "memory");                              \
    LOADFRAGS_ASM(NA, NB, ((U) + 1) & 3);                                         \
    __builtin_amdgcn_sched_barrier(0);                                            \
    __builtin_amdgcn_s_setprio(1);                                                \
    MFMABLOCK(CA, CB)                                                             \
    __builtin_amdgcn_s_setprio(0);                                                \
    asm volatile("s_waitcnt lgkmcnt(0)" ::: "memory");                            \
    __builtin_amdgcn_sched_barrier(0);                                            \
    __builtin_amdgcn_s_barrier();                                                 \
} while (0)

__global__ __launch_bounds__(512, 2)
void gemm8p(const unsigned short* __restrict__ Abf, const unsigned short* __restrict__ Wb,
            float* __restrict__ out, int M, int N, int K) {
    __shared__ __align__(16) unsigned short sA[4 * 8192];  // 4 slots x 256m x 32k (kc swz)
    __shared__ __align__(16) unsigned short sB[4 * 8192];  // 4 slots x 4kc x 256n x 8

    const int tid  = threadIdx.x;
    const int lane = tid & 63;
    const int wid  = tid >> 6;
    const int wr   = wid >> 2;   // 0..1  (128-row half)
    const int wc   = wid & 3;    // 0..3  (64-col slice)
    const int r15  = lane & 15;
    const int hi   = lane >> 4;

    const int NBN = N / 256;
    int nwg = gridDim.x, orig = blockIdx.x;
    int wg = ((nwg & 7) == 0) ? (orig & 7) * (nwg >> 3) + (orig >> 3) : orig;
    const int m0 = (wg / NBN) * 256, n0 = (wg % NBN) * 256;

    const int NH = K / 32;  // 32-k halves (NH % 4 == 0)

    // per-lane ds_read byte bases (LDS address space)
    const int aoff = (wr * 128 + r15) * 32 + ((hi ^ ((r15 >> 1) & 3)) << 3);
    const int boff = hi * 2048 + (wc * 64 + r15) * 8;
    const unsigned aByte = (unsigned)(unsigned long long)
        ((__attribute__((address_space(3))) unsigned short*)sA + aoff);
    const unsigned bByte = (unsigned)(unsigned long long)
        ((__attribute__((address_space(3))) unsigned short*)sB + boff);

    // staging bases: 2 A + 2 B gload_lds per thread per half
    const int am  = tid >> 2, akc = tid & 3;
    const int akcs = (akc ^ ((am >> 1) & 3)) << 3;
    const unsigned short* baseA0 = Abf + (size_t)(m0 + am) * K + akcs;
    const unsigned short* baseA1 = Abf + (size_t)(m0 + am + 128) * K + akcs;
    const int bkc = tid >> 8, bn = tid & 255;
    const unsigned short* baseB0 = Wb + ((size_t)bkc * N + n0 + bn) * 8;
    const unsigned short* baseB1 = Wb + ((size_t)(bkc + 2) * N + n0 + bn) * 8;
    const size_t bstride = (size_t)32 * N;
    unsigned short* const dA = sA + wid * 512;
    unsigned short* const dB = sB + wid * 512;

    auto stage = [&](int S, int slot) {
        gload16(baseA0 + S * 32, dA + slot * 8192);
        gload16(baseB0 + S * bstride, dB + slot * 8192);
        gload16(baseA1 + S * 32, dA + slot * 8192 + 4096);
        gload16(baseB1 + S * bstride, dB + slot * 8192 + 4096);
    };

    f32x4 acc[8][4] = {};
    bf16x8 avA[8], bvA[4], avB[8], bvB[4];

    // prologue: stage halves 0,1,2 (12 loads); vmcnt(4) forces stage(0) AND
    // stage(1) before the barrier -> cross-wave proof for phase 0's slot-1
    // reads; barrier; plain-load frags(0) (compiler inserts lgkm wait).
    stage(0, 0);
    stage(1, 1);
    stage(2, 2);
    asm volatile("s_waitcnt vmcnt(4)" ::: "memory");
    __builtin_amdgcn_s_barrier();
#pragma unroll
    for (int nf = 0; nf < 4; ++nf) bvA[nf] = *(const bf16x8*)(sB + boff + nf * 128);
#pragma unroll
    for (int mf = 0; mf < 8; ++mf) avA[mf] = *(const bf16x8*)(sA + aoff + mf * 512);

    for (int H = 0; H < NH; H += 4) {
        PHASE(0, avA, bvA, avB, bvB);
        PHASE(1, avB, bvB, avA, bvA);
        PHASE(2, avA, bvA, avB, bvB);
        PHASE(3, avB, bvB, avA, bvA);
    }

    asm volatile("s_waitcnt vmcnt(0) lgkmcnt(0)" ::: "memory");  // drain wrap prefetches

    // epilogue: C/D layout col=lane&15, row=(lane>>4)*4+reg
#pragma unroll
    for (int mf = 0; mf < 8; ++mf) {
        const int mrow = m0 + wr * 128 + mf * 16 + hi * 4;
#pragma unroll
        for (int nf = 0; nf < 4; ++nf) {
            const int ncol = n0 + wc * 64 + nf * 16 + r15;
            float* po = out + (size_t)mrow * N + ncol;
#pragma unroll
            for (int r = 0; r < 4; ++r) po[(size_t)r * N] = acc[mf][nf][r];
        }
    }
}

#undef PHASE
#undef MFMABLOCK
#undef LOADFRAGS_ASM
#undef DSR

// ---------------- fallback fused kernel (small ws only) ----------------

#define FBM 128
#define FBN 128
#define FBK 64

__device__ __forceinline__ int fswz(int row, int kb) {
    return row * (FBK * 2) + (kb ^ ((row & 7) << 4));
}

__global__ __launch_bounds__(256, 2)
void sqllm_gemm_fused(const float* __restrict__ A, const int* __restrict__ Q,
                      const float* __restrict__ lut, float* __restrict__ out,
                      int M, int N, int K) {
    __shared__ __align__(16) char sA[FBM * FBK * 2];
    __shared__ __align__(16) char sB[FBN * FBK * 2];
    __shared__ float sLut[FBN * 17];

    const int tid  = threadIdx.x;
    const int lane = tid & 63;
    const int wid  = tid >> 6;
    const int wr   = wid >> 1;
    const int wc   = wid & 1;
    const int n0 = blockIdx.x * FBN;
    const int m0 = blockIdx.y * FBM;

    for (int i = tid; i < FBN * 16; i += 256) {
        int n = i >> 4, c = i & 15;
        sLut[n * 17 + c] = lut[(long)(n0 + n) * 16 + c];
    }
    __syncthreads();

    f32x4 acc[4][4] = {};
    const int nK = K / FBK;
    for (int kk = 0; kk < nK; ++kk) {
        {
            const int r = tid >> 1, h = tid & 1;
            const float* ap = A + (long)(m0 + r) * K + kk * FBK + h * 32;
            f32x4 v[8];
#pragma unroll
            for (int j = 0; j < 8; ++j) v[j] = reinterpret_cast<const f32x4*>(ap)[j];
            const int kr = tid >> 5, nq = (tid & 31) << 2;
            const int* qp = Q + (long)(kk * (FBK / 8) + kr) * N + n0 + nq;
            i32x4 q = *reinterpret_cast<const i32x4*>(qp);
#pragma unroll
            for (int j = 0; j < 4; ++j) {
                bf16x8 e;
#pragma unroll
                for (int x = 0; x < 4; ++x) {
                    e[x]     = (short)f2bf(v[2 * j][x]);
                    e[4 + x] = (short)f2bf(v[2 * j + 1][x]);
                }
                *reinterpret_cast<bf16x8*>(sA + fswz(r, h * 64 + j * 16)) = e;
            }
#pragma unroll
            for (int c = 0; c < 4; ++c) {
                const int n = nq + c;
                const float* lp = sLut + n * 17;
                unsigned int qq = (unsigned int)q[c];
                bf16x8 w;
#pragma unroll
                for (int p = 0; p < 8; ++p)
                    w[p] = (short)f2bf(lp[(qq >> (4 * p)) & 15]);
                *reinterpret_cast<bf16x8*>(sB + fswz(n, kr * 16)) = w;
            }
        }
        __syncthreads();
#pragma unroll
        for (int kh = 0; kh < 2; ++kh) {
            const int kb = kh * 64 + (lane >> 4) * 16;
            bf16x8 af[4], bfv[4];
#pragma unroll
            for (int i = 0; i < 4; ++i) {
                af[i]  = *reinterpret_cast<const bf16x8*>(sA + fswz(wr * 64 + i * 16 + (lane & 15), kb));
                bfv[i] = *reinterpret_cast<const bf16x8*>(sB + fswz(wc * 64 + i * 16 + (lane & 15), kb));
            }
#pragma unroll
            for (int i = 0; i < 4; ++i)
#pragma unroll
                for (int j = 0; j < 4; ++j)
                    acc[i][j] = __builtin_amdgcn_mfma_f32_16x16x32_bf16(af[i], bfv[j], acc[i][j], 0, 0, 0);
        }
        __syncthreads();
    }
    const int col = lane & 15;
    const int r4  = (lane >> 4) * 4;
#pragma unroll
    for (int i = 0; i < 4; ++i) {
        const int mrow = m0 + wr * 64 + i * 16 + r4;
#pragma unroll
        for (int j = 0; j < 4; ++j) {
            const int ncol = n0 + wc * 64 + j * 16 + col;
#pragma unroll
            for (int r = 0; r < 4; ++r)
                out[(long)(mrow + r) * N + ncol] = acc[i][j][r];
        }
    }
}

extern "C" void kernel_launch(void* const* d_in, const int* in_sizes, int n_in,
                              void* d_out, int out_size, void* d_ws, size_t ws_size,
                              hipStream_t stream) {
    const float* A   = (const float*)d_in[0];
    const int*   Q   = (const int*)d_in[1];
    const float* lut = (const float*)d_in[2];
    float* out = (float*)d_out;

    const long szA = in_sizes[0], szQ = in_sizes[1], szL = in_sizes[2];
    const int N = (int)(szL / 16);
    const int K = (int)(szQ * 8 / N);
    const int M = (int)(szA / K);

    const size_t needA = (size_t)M * K * 2;
    const size_t needW = (size_t)K * N * 2;

    const bool shape_ok = (M % 256 == 0) && (N % 256 == 0) && (K % 128 == 0);

    if (shape_ok && ws_size >= needA + needW) {
        unsigned short* Abf = (unsigned short*)d_ws;
        unsigned short* Wb  = (unsigned short*)((char*)d_ws + needA);
        const long n8 = (long)M * K / 8;
        convA_kernel<<<2048, 256, 0, stream>>>(A, Abf, n8);
        const long tq = (long)(K / 8) * N;
        dequantW_kernel<<<(int)((tq + 255) / 256), 256, 0, stream>>>(Q, lut, Wb, N, tq);
        dim3 grid((M / 256) * (N / 256));
        gemm8p<<<grid, 512, 0, stream>>>(Abf, Wb, out, M, N, K);
    } else {
        dim3 grid(N / FBN, M / FBM);
        sqllm_gemm_fused<<<grid, 256, 0, stream>>>(A, Q, lut, out, M, N, K);
    }
}

// Round 19
// 274.325 us; speedup vs baseline: 1.1151x; 1.0198x over previous
//
#include <hip/hip_runtime.h>
#include <hip/hip_bf16.h>

// sqllm 4-bit GEMM: out[m,n] = sum_k A[m,k] * lut[n, nibble(qweight[k/8,n], k%8)]
// M=8192, N=4096, K=4096. PRE path: A->bf16, W dequant once into ws.
// GEMM: 256x256, 8 waves, 4-slot LDS ring, all global_load_lds staging,
// 16x16x32 MFMA, proven vmcnt(4) ledger (R18). R19: issue the 12 asm
// ds_reads FIRST in the phase (their data was forced complete before the
// PREVIOUS phase's barrier) so the DS unit gets a head start and the
// vmcnt(4) wait overlaps DS processing; setprio(1) widened over read-issue.
// Safe-rules (3 corruption episodes): DSRs clustered at phase boundary only;
// lgkm only as full drain; counted vmcnt only over pure-gload_lds ledgers.

typedef __attribute__((ext_vector_type(4))) float  f32x4;
typedef __attribute__((ext_vector_type(4))) int    i32x4;
typedef __attribute__((ext_vector_type(8))) short  bf16x8;

__device__ __forceinline__ unsigned short f2bf(float f) {
    __hip_bfloat16 h = __float2bfloat16(f);
    return __builtin_bit_cast(unsigned short, h);
}

__device__ __forceinline__ void gload16(const unsigned short* g, unsigned short* l) {
    __builtin_amdgcn_global_load_lds(
        (const __attribute__((address_space(1))) unsigned int*)g,
        (__attribute__((address_space(3))) unsigned int*)l, 16, 0, 0);
}

// ---------------- prepass kernels ----------------

__global__ void convA_kernel(const float* __restrict__ in, unsigned short* __restrict__ o, long n8) {
    long i = (long)blockIdx.x * blockDim.x + threadIdx.x;
    long stride = (long)gridDim.x * blockDim.x;
    const f32x4* in4 = reinterpret_cast<const f32x4*>(in);
    bf16x8* o8 = reinterpret_cast<bf16x8*>(o);
    for (; i < n8; i += stride) {
        f32x4 a = in4[2 * i];
        f32x4 b = in4[2 * i + 1];
        bf16x8 e;
#pragma unroll
        for (int x = 0; x < 4; ++x) {
            e[x]     = (short)f2bf(a[x]);
            e[4 + x] = (short)f2bf(b[x]);
        }
        o8[i] = e;
    }
}

__global__ void dequantW_kernel(const int* __restrict__ Q, const float* __restrict__ lut,
                                unsigned short* __restrict__ Wb, int N, long total) {
    long i = (long)blockIdx.x * blockDim.x + threadIdx.x;
    if (i >= total) return;
    unsigned int v = (unsigned int)Q[i];
    int n = (int)(i % N);
    const float* lp = lut + (long)n * 16;
    bf16x8 w;
#pragma unroll
    for (int p = 0; p < 8; ++p)
        w[p] = (short)f2bf(lp[(v >> (4 * p)) & 15]);
    reinterpret_cast<bf16x8*>(Wb)[i] = w;
}

// ---------------- 256x256 GEMM, DSR-first pipelined phases ----------------
// Half H -> slot H&3. Phase H:
//   setprio(1)
//   12x asm ds_read_b128 (slot (H+1)&3) -> alt regs   [data proven resident:
//       stage(H+1) forced by phase H-1's vmcnt(4) BEFORE its barrier]
//   stage(H+3)  [4 gload_lds]
//   vmcnt(4)    (outstanding {stage(H+2),stage(H+3)}=8 -> forces stage(H+2))
//   sched_barrier; 32 MFMA on current regs; setprio(0)
//   lgkmcnt(0); sched_barrier; s_barrier
// WAR: slot (H+1)'s reads drain at this phase's lgkmcnt(0), >=1 barrier
// before its re-staging in phase H+2. Register WAR vs phase H-1's MFMAs:
// DSRs sit at the phase boundary (post-barrier) - the empirically safe spot.

#define DSR(dst, addr, OFF) \
    asm volatile("ds_read_b128 %0, %1 offset:" #OFF : "=v"(dst) : "v"(addr))

#define LOADFRAGS_ASM(NA, NB, SLOT) do {                                          \
    unsigned ab_ = aByte + (unsigned)(SLOT) * 16384u;                             \
    unsigned bb_ = bByte + (unsigned)(SLOT) * 16384u;                             \
    DSR(NB[0], bb_, 0);    DSR(NB[1], bb_, 256);                                  \
    DSR(NB[2], bb_, 512);  DSR(NB[3], bb_, 768);                                  \
    DSR(NA[0], ab_, 0);    DSR(NA[1], ab_, 1024);                                 \
    DSR(NA[2], ab_, 2048); DSR(NA[3], ab_, 3072);                                 \
    DSR(NA[4], ab_, 4096); DSR(NA[5], ab_, 5120);                                 \
    DSR(NA[6], ab_, 6144); DSR(NA[7], ab_, 7168);                                 \
} while (0)

#define MFMABLOCK(CA, CB)                                                         \
    _Pragma("unroll") for (int mf = 0; mf < 8; ++mf)                              \
        _Pragma("unroll") for (int nf = 0; nf < 4; ++nf)                          \
            acc[mf][nf] = __builtin_amdgcn_mfma_f32_16x16x32_bf16(                \
                CA[mf], CB[nf], acc[mf][nf], 0, 0, 0);

#define PHASE(U, CA, CB, NA, NB) do {                                             \
    __builtin_amdgcn_s_setprio(1);                                                \
    LOADFRAGS_ASM(NA, NB, ((U) + 1) & 3);                                         \
    __builtin_amdgcn_sched_barrier(0);                                            \
    int S3 = H + (U) + 3; if (S3 >= NH) S3 -= NH;                                 \
    stage(S3, ((U) + 3) & 3);                                                     \
    asm volatile("s_waitcnt vmcnt(4)" ::: "memory");                              \
    __builtin_amdgcn_sched_barrier(0);                                            \
    MFMABLOCK(CA, CB)                                                             \
    __builtin_amdgcn_s_setprio(0);                                                \
    asm volatile("s_waitcnt lgkmcnt(0)" ::: "memory");                            \
    __builtin_amdgcn_sched_barrier(0);                                            \
    __builtin_amdgcn_s_barrier();                                                 \
} while (0)

__global__ __launch_bounds__(512, 2)
void gemm8p(const unsigned short* __restrict__ Abf, const unsigned short* __restrict__ Wb,
            float* __restrict__ out, int M, int N, int K) {
    __shared__ __align__(16) unsigned short sA[4 * 8192];  // 4 slots x 256m x 32k (kc swz)
    __shared__ __align__(16) unsigned short sB[4 * 8192];  // 4 slots x 4kc x 256n x 8

    const int tid  = threadIdx.x;
    const int lane = tid & 63;
    const int wid  = tid >> 6;
    const int wr   = wid >> 2;   // 0..1  (128-row half)
    const int wc   = wid & 3;    // 0..3  (64-col slice)
    const int r15  = lane & 15;
    const int hi   = lane >> 4;

    const int NBN = N / 256;
    int nwg = gridDim.x, orig = blockIdx.x;
    int wg = ((nwg & 7) == 0) ? (orig & 7) * (nwg >> 3) + (orig >> 3) : orig;
    const int m0 = (wg / NBN) * 256, n0 = (wg % NBN) * 256;

    const int NH = K / 32;  // 32-k halves (NH % 4 == 0)

    // per-lane ds_read byte bases (LDS address space)
    const int aoff = (wr * 128 + r15) * 32 + ((hi ^ ((r15 >> 1) & 3)) << 3);
    const int boff = hi * 2048 + (wc * 64 + r15) * 8;
    const unsigned aByte = (unsigned)(unsigned long long)
        ((__attribute__((address_space(3))) unsigned short*)sA + aoff);
    const unsigned bByte = (unsigned)(unsigned long long)
        ((__attribute__((address_space(3))) unsigned short*)sB + boff);

    // staging bases: 2 A + 2 B gload_lds per thread per half
    const int am  = tid >> 2, akc = tid & 3;
    const int akcs = (akc ^ ((am >> 1) & 3)) << 3;
    const unsigned short* baseA0 = Abf + (size_t)(m0 + am) * K + akcs;
    const unsigned short* baseA1 = Abf + (size_t)(m0 + am + 128) * K + akcs;
    const int bkc = tid >> 8, bn = tid & 255;
    const unsigned short* baseB0 = Wb + ((size_t)bkc * N + n0 + bn) * 8;
    const unsigned short* baseB1 = Wb + ((size_t)(bkc + 2) * N + n0 + bn) * 8;
    const size_t bstride = (size_t)32 * N;
    unsigned short* const dA = sA + wid * 512;
    unsigned short* const dB = sB + wid * 512;

    auto stage = [&](int S, int slot) {
        gload16(baseA0 + S * 32, dA + slot * 8192);
        gload16(baseB0 + S * bstride, dB + slot * 8192);
        gload16(baseA1 + S * 32, dA + slot * 8192 + 4096);
        gload16(baseB1 + S * bstride, dB + slot * 8192 + 4096);
    };

    f32x4 acc[8][4] = {};
    bf16x8 avA[8], bvA[4], avB[8], bvB[4];

    // prologue: stage halves 0,1,2 (12 loads); vmcnt(4) forces stage(0) AND
    // stage(1) before the barrier; barrier; plain-load frags(0).
    stage(0, 0);
    stage(1, 1);
    stage(2, 2);
    asm volatile("s_waitcnt vmcnt(4)" ::: "memory");
    __builtin_amdgcn_s_barrier();
#pragma unroll
    for (int nf = 0; nf < 4; ++nf) bvA[nf] = *(const bf16x8*)(sB + boff + nf * 128);
#pragma unroll
    for (int mf = 0; mf < 8; ++mf) avA[mf] = *(const bf16x8*)(sA + aoff + mf * 512);

    for (int H = 0; H < NH; H += 4) {
        PHASE(0, avA, bvA, avB, bvB);
        PHASE(1, avB, bvB, avA, bvA);
        PHASE(2, avA, bvA, avB, bvB);
        PHASE(3, avB, bvB, avA, bvA);
    }

    asm volatile("s_waitcnt vmcnt(0) lgkmcnt(0)" ::: "memory");  // drain wrap prefetches

    // epilogue: C/D layout col=lane&15, row=(lane>>4)*4+reg
#pragma unroll
    for (int mf = 0; mf < 8; ++mf) {
        const int mrow = m0 + wr * 128 + mf * 16 + hi * 4;
#pragma unroll
        for (int nf = 0; nf < 4; ++nf) {
            const int ncol = n0 + wc * 64 + nf * 16 + r15;
            float* po = out + (size_t)mrow * N + ncol;
#pragma unroll
            for (int r = 0; r < 4; ++r) po[(size_t)r * N] = acc[mf][nf][r];
        }
    }
}

#undef PHASE
#undef MFMABLOCK
#undef LOADFRAGS_ASM
#undef DSR

// ---------------- fallback fused kernel (small ws only) ----------------

#define FBM 128
#define FBN 128
#define FBK 64

__device__ __forceinline__ int fswz(int row, int kb) {
    return row * (FBK * 2) + (kb ^ ((row & 7) << 4));
}

__global__ __launch_bounds__(256, 2)
void sqllm_gemm_fused(const float* __restrict__ A, const int* __restrict__ Q,
                      const float* __restrict__ lut, float* __restrict__ out,
                      int M, int N, int K) {
    __shared__ __align__(16) char sA[FBM * FBK * 2];
    __shared__ __align__(16) char sB[FBN * FBK * 2];
    __shared__ float sLut[FBN * 17];

    const int tid  = threadIdx.x;
    const int lane = tid & 63;
    const int wid  = tid >> 6;
    const int wr   = wid >> 1;
    const int wc   = wid & 1;
    const int n0 = blockIdx.x * FBN;
    const int m0 = blockIdx.y * FBM;

    for (int i = tid; i < FBN * 16; i += 256) {
        int n = i >> 4, c = i & 15;
        sLut[n * 17 + c] = lut[(long)(n0 + n) * 16 + c];
    }
    __syncthreads();

    f32x4 acc[4][4] = {};
    const int nK = K / FBK;
    for (int kk = 0; kk < nK; ++kk) {
        {
            const int r = tid >> 1, h = tid & 1;
            const float* ap = A + (long)(m0 + r) * K + kk * FBK + h * 32;
            f32x4 v[8];
#pragma unroll
            for (int j = 0; j < 8; ++j) v[j] = reinterpret_cast<const f32x4*>(ap)[j];
            const int kr = tid >> 5, nq = (tid & 31) << 2;
            const int* qp = Q + (long)(kk * (FBK / 8) + kr) * N + n0 + nq;
            i32x4 q = *reinterpret_cast<const i32x4*>(qp);
#pragma unroll
            for (int j = 0; j < 4; ++j) {
                bf16x8 e;
#pragma unroll
                for (int x = 0; x < 4; ++x) {
                    e[x]     = (short)f2bf(v[2 * j][x]);
                    e[4 + x] = (short)f2bf(v[2 * j + 1][x]);
                }
                *reinterpret_cast<bf16x8*>(sA + fswz(r, h * 64 + j * 16)) = e;
            }
#pragma unroll
            for (int c = 0; c < 4; ++c) {
                const int n = nq + c;
                const float* lp = sLut + n * 17;
                unsigned int qq = (unsigned int)q[c];
                bf16x8 w;
#pragma unroll
                for (int p = 0; p < 8; ++p)
                    w[p] = (short)f2bf(lp[(qq >> (4 * p)) & 15]);
                *reinterpret_cast<bf16x8*>(sB + fswz(n, kr * 16)) = w;
            }
        }
        __syncthreads();
#pragma unroll
        for (int kh = 0; kh < 2; ++kh) {
            const int kb = kh * 64 + (lane >> 4) * 16;
            bf16x8 af[4], bfv[4];
#pragma unroll
            for (int i = 0; i < 4; ++i) {
                af[i]  = *reinterpret_cast<const bf16x8*>(sA + fswz(wr * 64 + i * 16 + (lane & 15), kb));
                bfv[i] = *reinterpret_cast<const bf16x8*>(sB + fswz(wc * 64 + i * 16 + (lane & 15), kb));
            }
#pragma unroll
            for (int i = 0; i < 4; ++i)
#pragma unroll
                for (int j = 0; j < 4; ++j)
                    acc[i][j] = __builtin_amdgcn_mfma_f32_16x16x32_bf16(af[i], bfv[j], acc[i][j], 0, 0, 0);
        }
        __syncthreads();
    }
    const int col = lane & 15;
    const int r4  = (lane >> 4) * 4;
#pragma unroll
    for (int i = 0; i < 4; ++i) {
        const int mrow = m0 + wr * 64 + i * 16 + r4;
#pragma unroll
        for (int j = 0; j < 4; ++j) {
            const int ncol = n0 + wc * 64 + j * 16 + col;
#pragma unroll
            for (int r = 0; r < 4; ++r)
                out[(long)(mrow + r) * N + ncol] = acc[i][j][r];
        }
    }
}

extern "C" void kernel_launch(void* const* d_in, const int* in_sizes, int n_in,
                              void* d_out, int out_size, void* d_ws, size_t ws_size,
                              hipStream_t stream) {
    const float* A   = (const float*)d_in[0];
    const int*   Q   = (const int*)d_in[1];
    const float* lut = (const float*)d_in[2];
    float* out = (float*)d_out;

    const long szA = in_sizes[0], szQ = in_sizes[1], szL = in_sizes[2];
    const int N = (int)(szL / 16);
    const int K = (int)(szQ * 8 / N);
    const int M = (int)(szA / K);

    const size_t needA = (size_t)M * K * 2;
    const size_t needW = (size_t)K * N * 2;

    const bool shape_ok = (M % 256 == 0) && (N % 256 == 0) && (K % 128 == 0);

    if (shape_ok && ws_size >= needA + needW) {
        unsigned short* Abf = (unsigned short*)d_ws;
        unsigned short* Wb  = (unsigned short*)((char*)d_ws + needA);
        const long n8 = (long)M * K / 8;
        convA_kernel<<<2048, 256, 0, stream>>>(A, Abf, n8);
        const long tq = (long)(K / 8) * N;
        dequantW_kernel<<<(int)((tq + 255) / 256), 256, 0, stream>>>(Q, lut, Wb, N, tq);
        dim3 grid((M / 256) * (N / 256));
        gemm8p<<<grid, 512, 0, stream>>>(Abf, Wb, out, M, N, K);
    } else {
        dim3 grid(N / FBN, M / FBM);
        sqllm_gemm_fused<<<grid, 256, 0, stream>>>(A, Q, lut, out, M, N, K);
    }
}